// Round 5
// baseline (90.664 us; speedup 1.0000x reference)
//
#include <hip/hip_runtime.h>

#define D    32       // feature dim (fixed)
#define BLK  256      // threads per block (4 waves; block = 64 i-rows)
#define NCH  16       // j-chunks per batch -> grid.y
#define LOG2E 1.44269504088896340736f

typedef short  short8  __attribute__((ext_vector_type(8)));
typedef float  floatx4 __attribute__((ext_vector_type(4)));
typedef float  v2f     __attribute__((ext_vector_type(2)));

__device__ __forceinline__ short f2bf(float v) {       // fp32 -> bf16 (RTNE-ish)
    union { float f; unsigned u; } x; x.f = v;
    unsigned r = x.u + 0x7fffu + ((x.u >> 16) & 1u);
    return (short)(r >> 16);
}
__device__ __forceinline__ float bf2f(short h) {
    union { float f; unsigned u; } x;
    x.u = ((unsigned)(unsigned short)h) << 16;
    return x.f;
}
__device__ __forceinline__ float fast_exp2(float x) {
#if __has_builtin(__builtin_amdgcn_exp2f)
    return __builtin_amdgcn_exp2f(x);
#else
    return exp2f(x);
#endif
}

// ---------------------------------------------------------------------------
// Kernel P: per-row precompute + zero-init + bf16 hi/lo split of BOTH feature
// arrays, stored FRAGMENT-MAJOR: row n (tile t=n/16, m=n%16), k-octet q ->
// slot l=m+16q of tile t at gX[(t*64+l)*8 .. +8). The pair kernel then reads
// MFMA operands directly from global with lane-contiguous 16B loads.
//   xp[r]  = (20*px, 20*py, 20*pz, log2e*|20*p|^2)
//   f1n[r] = log2e*|fea1_r|^2,  f2n[r] = log2e*|fea2_r|^2
// ---------------------------------------------------------------------------
__global__ __launch_bounds__(BLK) void precompute_kernel(
    const float* __restrict__ points,
    const float* __restrict__ fea1,
    const float* __restrict__ fea2,
    float4* __restrict__ xp,
    float* __restrict__ f1n,
    float* __restrict__ f2n,
    short* __restrict__ f1hi,
    short* __restrict__ f1lo,
    short* __restrict__ f2hi,
    short* __restrict__ f2lo,
    float* __restrict__ acc,
    float* __restrict__ out,
    int BN, int Bsz)
{
    int r = blockIdx.x * BLK + threadIdx.x;
    if (r < Bsz) out[r] = 0.0f;
    if (r >= BN) return;
#pragma unroll
    for (int s = 0; s < 5; ++s) acc[s * BN + r] = 0.0f;

    const float s20 = 20.0f;                 // 1/SIGMA
    float x = points[3*r+0] * s20;
    float y = points[3*r+1] * s20;
    float z = points[3*r+2] * s20;
    float4 v; v.x = x; v.y = y; v.z = z;
    v.w = (x*x + y*y + z*z) * LOG2E;
    xp[r] = v;

    const int t = r >> 4;                    // global 16-row tile id
    const int m = r & 15;
    const float* p1 = fea1 + (size_t)r * D;
    const float* p2 = fea2 + (size_t)r * D;
    float n1 = 0.f, n2 = 0.f;
#pragma unroll
    for (int q = 0; q < 4; ++q) {
        size_t off = ((size_t)t * 64 + m + 16*q) * 8;
        float4 a0 = *(const float4*)(p1 + q*8);
        float4 a1 = *(const float4*)(p1 + q*8 + 4);
        float e1[8] = {a0.x,a0.y,a0.z,a0.w,a1.x,a1.y,a1.z,a1.w};
        short8 h1, l1;
#pragma unroll
        for (int k = 0; k < 8; ++k) {
            n1 = fmaf(e1[k], e1[k], n1);
            short hh = f2bf(e1[k]);
            h1[k] = hh;
            l1[k] = f2bf(e1[k] - bf2f(hh));
        }
        *(short8*)&f1hi[off] = h1;
        *(short8*)&f1lo[off] = l1;

        float4 b0 = *(const float4*)(p2 + q*8);
        float4 b1 = *(const float4*)(p2 + q*8 + 4);
        float e2[8] = {b0.x,b0.y,b0.z,b0.w,b1.x,b1.y,b1.z,b1.w};
        short8 h2, l2;
#pragma unroll
        for (int k = 0; k < 8; ++k) {
            n2 = fmaf(e2[k], e2[k], n2);
            short hh = f2bf(e2[k]);
            h2[k] = hh;
            l2[k] = f2bf(e2[k] - bf2f(hh));
        }
        *(short8*)&f2hi[off] = h2;
        *(short8*)&f2lo[off] = l2;
    }
    f1n[r] = n1 * LOG2E;
    f2n[r] = n2 * LOG2E;
}

// ---------------------------------------------------------------------------
// Kernel A: pair loop, NO LDS. Block = 64 i-rows x JCH j's; each wave owns
// JCH/64 j-tiles and sweeps ALL 4 i-tiles of the block, so A-frags + spatial
// data (j-only) are loaded once per j-tile and reused 4x. All operands come
// pre-split fragment-major from global (L2-resident, ~2.4 MB), so there is
// no staging, no barrier, no conversion in the hot loop.
// Feature dot via split-bf16 MFMA (hi*hi + hi*lo + lo*hi); spatial logit
// stays per-pair fp32 VALU (cancellation-sensitive, keeps absmax 0).
// ---------------------------------------------------------------------------
__global__ __launch_bounds__(BLK) void pair_kernel(
    const short* __restrict__ f1hi,
    const short* __restrict__ f1lo,
    const short* __restrict__ f2hi,
    const short* __restrict__ f2lo,
    const float4* __restrict__ xp,
    const float* __restrict__ f1n,
    const float* __restrict__ f2n,
    float* __restrict__ acc,
    int N, int BN)
{
    const int tid  = threadIdx.x;
    const int lane = tid & 63;
    const int wv   = tid >> 6;
    const int m    = lane & 15;        // i-offset within tile (C col)
    const int q    = lane >> 4;        // k-octet / j-quad (C row group)

    const int ibpb  = N >> 6;          // i-blocks per batch
    const int b     = blockIdx.x / ibpb;
    const int ibase = blockIdx.x << 6; // global row base (batch included)
    const int JCH   = N / NCH;
    const int jc0   = blockIdx.y * JCH;

    const float L2 = 2.0f * LOG2E;

    // ---- per-wave persistent state: B-frags + spatial i-data for 4 i-tiles
    short8 Bh[4], Bl[4];
    float xsx[4], xsy[4], xsz[4], mw[4], nf[4];
#pragma unroll
    for (int it = 0; it < 4; ++it) {
        size_t ti = ((size_t)(blockIdx.x * 4 + it) * 64 + lane) * 8;
        Bh[it] = *(const short8*)&f1hi[ti];
        Bl[it] = *(const short8*)&f1lo[ti];
        int irow = ibase + it*16 + m;
        float4 xi = xp[irow];
        xsx[it] = xi.x * L2; xsy[it] = xi.y * L2; xsz[it] = xi.z * L2;
        mw[it] = -xi.w;
        nf[it] = -f1n[irow];
    }

    v2f  sAB[4] = {{0.f,0.f},{0.f,0.f},{0.f,0.f},{0.f,0.f}};  // (sum e^a, sum e^b)
    v2f  s2 [4] = {{0.f,0.f},{0.f,0.f},{0.f,0.f},{0.f,0.f}};  // (sum e^2a, e^2b)
    float sab[4] = {0.f,0.f,0.f,0.f};                         // sum e^a e^b

    const int ntw    = JCH >> 6;               // j-tiles per wave
    const int tjbase = (b * N + jc0) >> 4;     // global j-tile base

    for (int t = 0; t < ntw; ++t) {
        const int jt = wv * ntw + t;
        const size_t tj = ((size_t)(tjbase + jt) * 64 + lane) * 8;
        short8 Ah = *(const short8*)&f2hi[tj];
        short8 Al = *(const short8*)&f2lo[tj];

        const int jb = b * N + jc0 + jt * 16 + q * 4;   // this lane's 4 j's
        float4 xjv[4];
        xjv[0] = xp[jb+0]; xjv[1] = xp[jb+1]; xjv[2] = xp[jb+2]; xjv[3] = xp[jb+3];
        floatx4 fnr = *(const floatx4*)&f2n[jb];

#pragma unroll
        for (int it = 0; it < 4; ++it) {
            floatx4 c = {0.f, 0.f, 0.f, 0.f};
            c = __builtin_amdgcn_mfma_f32_16x16x32_bf16(Ah, Bh[it], c, 0, 0, 0);
            c = __builtin_amdgcn_mfma_f32_16x16x32_bf16(Ah, Bl[it], c, 0, 0, 0);
            c = __builtin_amdgcn_mfma_f32_16x16x32_bf16(Al, Bh[it], c, 0, 0, 0);
#pragma unroll
            for (int r = 0; r < 4; ++r) {
                float aL = fmaf(xsz[it], xjv[r].z,
                             fmaf(xsy[it], xjv[r].y,
                              fmaf(xsx[it], xjv[r].x, mw[it]))) - xjv[r].w;
                float bL = fmaf(c[r], L2, nf[it] - fnr[r]);
                float ea = fast_exp2(aL);
                float eb = fast_exp2(bL);
                v2f e = {ea, eb};
                sAB[it] += e;                                    // v_pk_add_f32
                s2[it]   = __builtin_elementwise_fma(e, e, s2[it]); // v_pk_fma
                sab[it]  = fmaf(ea, eb, sab[it]);
            }
        }
    }

    // ---- reduce the 4 j-quads (lanes sharing lane&15), then atomics ----
#pragma unroll
    for (int it = 0; it < 4; ++it) {
        float vA = sAB[it].x, vB = sAB[it].y;
        float v2a = s2[it].x, v2b = s2[it].y, vab = sab[it];
        vA  += __shfl_xor(vA, 16);  vA  += __shfl_xor(vA, 32);
        vB  += __shfl_xor(vB, 16);  vB  += __shfl_xor(vB, 32);
        v2a += __shfl_xor(v2a, 16); v2a += __shfl_xor(v2a, 32);
        v2b += __shfl_xor(v2b, 16); v2b += __shfl_xor(v2b, 32);
        vab += __shfl_xor(vab, 16); vab += __shfl_xor(vab, 32);
        if (lane < 16) {
            int row = ibase + it*16 + lane;
            atomicAdd(&acc[0*BN + row], vA);
            atomicAdd(&acc[1*BN + row], v2a);
            atomicAdd(&acc[2*BN + row], vB);
            atomicAdd(&acc[3*BN + row], v2b);
            atomicAdd(&acc[4*BN + row], vab);
        }
    }
}

// ---------------------------------------------------------------------------
// Kernel B: combine per-row sums, weight, reduce into out[b] (out zeroed by P).
//   out[b] = sum_i w_i * ( S2a/A^2 - 2*Sab/(A*B) + S2b/B^2 )
// ---------------------------------------------------------------------------
__global__ __launch_bounds__(BLK) void finalize_kernel(
    const float* __restrict__ acc,
    const float* __restrict__ weights,
    float* __restrict__ out,
    int N, int BN)
{
    int row = blockIdx.x * BLK + threadIdx.x;
    int b   = (blockIdx.x * BLK) / N;

    float A   = acc[0*BN + row];
    float S2a = acc[1*BN + row];
    float Bt  = acc[2*BN + row];
    float S2b = acc[3*BN + row];
    float Sab = acc[4*BN + row];
    float invA = 1.0f / A;
    float invB = 1.0f / Bt;
    float val  = S2a*invA*invA - 2.0f*Sab*invA*invB + S2b*invB*invB;
    float sum  = weights[row] * val;

    __shared__ float red[BLK/64];
    for (int off = 32; off > 0; off >>= 1)
        sum += __shfl_down(sum, off);
    if ((threadIdx.x & 63) == 0) red[threadIdx.x >> 6] = sum;
    __syncthreads();
    if (threadIdx.x == 0) {
        float s = 0.f;
#pragma unroll
        for (int w = 0; w < BLK/64; ++w) s += red[w];
        atomicAdd(&out[b], s);
    }
}

// ---------------------------------------------------------------------------
extern "C" void kernel_launch(void* const* d_in, const int* in_sizes, int n_in,
                              void* d_out, int out_size, void* d_ws, size_t ws_size,
                              hipStream_t stream) {
    const float* points  = (const float*)d_in[0];
    const float* fea1    = (const float*)d_in[1];
    const float* fea2    = (const float*)d_in[2];
    const float* weights = (const float*)d_in[3];
    float* out = (float*)d_out;

    int B  = out_size;          // 2
    int BN = in_sizes[3];       // B*N = 8192
    int N  = BN / B;            // 4096

    // workspace (bytes):
    //   acc  : 5*BN*4   @ 0
    //   xp   : 4*BN*4   @ 5*BN*4
    //   f2n  : BN*4     @ 9*BN*4
    //   f1n  : BN*4     @ 10*BN*4
    //   f1hi : BN*D*2   @ 11*BN*4
    //   f1lo : BN*D*2
    //   f2hi : BN*D*2
    //   f2lo : BN*D*2
    float*  acc  = (float*)d_ws;
    float4* xp   = (float4*)((char*)d_ws + (size_t)5  * BN * 4);
    float*  f2n  = (float*)((char*)d_ws + (size_t)9  * BN * 4);
    float*  f1n  = (float*)((char*)d_ws + (size_t)10 * BN * 4);
    short*  f1hi = (short*)((char*)d_ws + (size_t)11 * BN * 4);
    short*  f1lo = f1hi + (size_t)BN * D;
    short*  f2hi = f1lo + (size_t)BN * D;
    short*  f2lo = f2hi + (size_t)BN * D;

    precompute_kernel<<<dim3((BN + BLK - 1) / BLK), dim3(BLK), 0, stream>>>(
        points, fea1, fea2, xp, f1n, f2n, f1hi, f1lo, f2hi, f2lo, acc, out, BN, B);

    dim3 grid(BN / 64, NCH);    // 128 x 16 = 2048 blocks
    pair_kernel<<<grid, dim3(BLK), 0, stream>>>(
        f1hi, f1lo, f2hi, f2lo, xp, f1n, f2n, acc, N, BN);

    finalize_kernel<<<dim3(BN / BLK), dim3(BLK), 0, stream>>>(acc, weights, out, N, BN);
}

// Round 7
// 86.735 us; speedup vs baseline: 1.0453x; 1.0453x over previous
//
#include <hip/hip_runtime.h>

#define D    32       // feature dim (fixed)
#define BLK  256      // threads per block (4 waves; wave = one 16-row i-tile)
#define NCH  8        // j-chunks per batch -> grid.y (1024 blocks total)
#define STJ  64       // j-rows per LDS stage (4 MFMA tiles)
#define LOG2E 1.44269504088896340736f

typedef short short8  __attribute__((ext_vector_type(8)));
typedef float floatx4 __attribute__((ext_vector_type(4)));
typedef float v2f     __attribute__((ext_vector_type(2)));

__device__ __forceinline__ short f2bf(float v) {       // fp32 -> bf16 (RTNE-ish)
    union { float f; unsigned u; } x; x.f = v;
    unsigned r = x.u + 0x7fffu + ((x.u >> 16) & 1u);
    return (short)(r >> 16);
}
__device__ __forceinline__ float bf2f(short h) {
    union { float f; unsigned u; } x;
    x.u = ((unsigned)(unsigned short)h) << 16;
    return x.f;
}
__device__ __forceinline__ float fast_exp2(float x) {
#if __has_builtin(__builtin_amdgcn_exp2f)
    return __builtin_amdgcn_exp2f(x);
#else
    return exp2f(x);
#endif
}

// ---------------------------------------------------------------------------
// Kernel P. Builds, per row, fragment-major MFMA operands so the pair kernel
// does NO conversion and almost NO per-pair VALU:
//
// Spatial (one 16x16x32 bf16 MFMA computes the ENTIRE log2 spatial logit):
//   x pre-scaled by s2l=sqrt(2*log2e), split 3-way h/l/ll;
//   xn = log2e*|x|^2 split 3-way (j-side) / 2-way (i-side):
//     A(j): k0-26 = [h,l,ll]x3 group-repeat, k27-29 = xn(h,m,l), k30-31 = -1
//     B(i): k0-8 = h'x3, k9-17 = l'x3, k18-26 = ll'x3, k27-29 = -1,
//           k30-31 = xn'(h,m)
//   sum_k A*B = 2log2e*<xi,xj> - xn_j - xn_i.  The i-side 2-term truncation
//   is a per-i constant -> cancels exactly in S2a/A^2 etc. (degree-0
//   homogeneous in per-row scaling).
//
// Feature: f pre-scaled by s2l, split h/l; dot via 3 MFMAs (hh'+hl'+lh');
// norms kept fp32 (fn2/nf1), seeded into the MFMA C input.
// Fragment-major layout: row n (tile t=n/16, m=n%16), k-octet q -> lane
// l=m+16q of tile t at arr[(t*64+l)*8 .. +8).
// ---------------------------------------------------------------------------
__global__ __launch_bounds__(BLK) void precompute_kernel(
    const float* __restrict__ points,
    const float* __restrict__ fea1,
    const float* __restrict__ fea2,
    short* __restrict__ sAj, short* __restrict__ sBi,
    short* __restrict__ fAh, short* __restrict__ fAl,
    short* __restrict__ fBh, short* __restrict__ fBl,
    float* __restrict__ fn2, float* __restrict__ nf1,
    float* __restrict__ acc, float* __restrict__ out,
    int BN, int Bsz)
{
    int r = blockIdx.x * BLK + threadIdx.x;
    if (r < Bsz) out[r] = 0.0f;
    if (r >= BN) return;
#pragma unroll
    for (int s = 0; s < 5; ++s) acc[s * BN + r] = 0.0f;

    const float s2l = sqrtf(2.0f * LOG2E);
    const int t = r >> 4, m = r & 15;
    const size_t fb = ((size_t)t * 64 + m) * 8;   // + q*128 per octet

    // ---- spatial ----
    float x0 = points[3*r+0] * 20.f;
    float x1 = points[3*r+1] * 20.f;
    float x2 = points[3*r+2] * 20.f;
    float xn = (x0*x0 + x1*x1 + x2*x2) * LOG2E;
    float xs[3] = {x0*s2l, x1*s2l, x2*s2l};
    short h[3], l[3], ll[3];
#pragma unroll
    for (int c = 0; c < 3; ++c) {
        h[c] = f2bf(xs[c]);
        float rm = xs[c] - bf2f(h[c]);
        l[c] = f2bf(rm);
        rm -= bf2f(l[c]);
        ll[c] = f2bf(rm);
    }
    short xnh = f2bf(xn);
    float rn = xn - bf2f(xnh);
    short xnm = f2bf(rn);
    rn -= bf2f(xnm);
    short xnl = f2bf(rn);
    const short N1 = (short)0xBF80;   // bf16 -1.0

    short8 aq[4], bq[4];
    aq[0] = (short8){h[0],h[1],h[2], l[0],l[1],l[2], ll[0],ll[1]};
    aq[1] = (short8){ll[2], h[0],h[1],h[2], l[0],l[1],l[2], ll[0]};
    aq[2] = (short8){ll[1],ll[2], h[0],h[1],h[2], l[0],l[1],l[2]};
    aq[3] = (short8){ll[0],ll[1],ll[2], xnh,xnm,xnl, N1,N1};
    bq[0] = (short8){h[0],h[1],h[2], h[0],h[1],h[2], h[0],h[1]};
    bq[1] = (short8){h[2], l[0],l[1],l[2], l[0],l[1],l[2], l[0]};
    bq[2] = (short8){l[1],l[2], ll[0],ll[1],ll[2], ll[0],ll[1],ll[2]};
    bq[3] = (short8){ll[0],ll[1],ll[2], N1,N1,N1, xnh,xnm};
#pragma unroll
    for (int q = 0; q < 4; ++q) {
        *(short8*)&sAj[fb + q*128] = aq[q];
        *(short8*)&sBi[fb + q*128] = bq[q];
    }

    // ---- features (f1 -> B side, f2 -> A side), scaled by s2l, h/l split ----
    const float* p1 = fea1 + (size_t)r * D;
    const float* p2 = fea2 + (size_t)r * D;
    float n1 = 0.f, n2 = 0.f;
#pragma unroll
    for (int q = 0; q < 4; ++q) {
        float4 a0 = *(const float4*)(p1 + q*8);
        float4 a1 = *(const float4*)(p1 + q*8 + 4);
        float e1[8] = {a0.x,a0.y,a0.z,a0.w,a1.x,a1.y,a1.z,a1.w};
        short8 hh1, ll1;
#pragma unroll
        for (int k = 0; k < 8; ++k) {
            n1 = fmaf(e1[k], e1[k], n1);
            float v = e1[k] * s2l;
            short hv = f2bf(v);
            hh1[k] = hv;
            ll1[k] = f2bf(v - bf2f(hv));
        }
        *(short8*)&fBh[fb + q*128] = hh1;
        *(short8*)&fBl[fb + q*128] = ll1;

        float4 b0 = *(const float4*)(p2 + q*8);
        float4 b1 = *(const float4*)(p2 + q*8 + 4);
        float e2[8] = {b0.x,b0.y,b0.z,b0.w,b1.x,b1.y,b1.z,b1.w};
        short8 hh2, ll2;
#pragma unroll
        for (int k = 0; k < 8; ++k) {
            n2 = fmaf(e2[k], e2[k], n2);
            float v = e2[k] * s2l;
            short hv = f2bf(v);
            hh2[k] = hv;
            ll2[k] = f2bf(v - bf2f(hv));
        }
        *(short8*)&fAh[fb + q*128] = hh2;
        *(short8*)&fAl[fb + q*128] = ll2;
    }
    nf1[r] = n1 * LOG2E;
    fn2[r] = n2 * LOG2E;
}

// ---------------------------------------------------------------------------
// Kernel A: pair loop, fully MFMA-ized logits.
//   Wave = one 16-row i-tile; block = 4 i-tiles x JCH j's.
//   Per 16x16 tile (256 pairs): 1 spatial MFMA (complete aL incl. norms),
//   3 feature MFMAs seeded with (-nf_i - fn_j), then per-pair just
//   2x exp2 + 3 accumulates. j-side frags staged in LDS, lane-contiguous
//   b128 reads (conflict-free).
//   NOTE: one 16-row j-tile = 64 lanes * 16B = 64 uint4 -> stage offset is
//   s0*4 uint4 (R6 bug: used 2x this, causing OOB reads -> NaN).
// ---------------------------------------------------------------------------
__global__ __launch_bounds__(BLK) void pair_kernel(
    const short* __restrict__ sAj,
    const short* __restrict__ fAh,
    const short* __restrict__ fAl,
    const short* __restrict__ sBi,
    const short* __restrict__ fBh,
    const short* __restrict__ fBl,
    const float* __restrict__ fn2,
    const float* __restrict__ nf1,
    float* __restrict__ acc,
    int N, int BN)
{
    __shared__ __align__(16) short lAs[STJ * D];  // 4 KB spatial A frags
    __shared__ __align__(16) short lAh[STJ * D];  // 4 KB feature A hi
    __shared__ __align__(16) short lAl[STJ * D];  // 4 KB feature A lo
    __shared__ float lFn[STJ];                    // 256 B fp32 fn2

    const int tid  = threadIdx.x;
    const int lane = tid & 63;
    const int wv   = tid >> 6;
    const int m    = lane & 15;        // i-offset (C col)
    const int q    = lane >> 4;        // j-quad (C row group)

    const int ibpb  = N >> 6;          // i-blocks per batch
    const int b     = blockIdx.x / ibpb;
    const int itile = blockIdx.x * 4 + wv;          // global 16-row i-tile
    const int JCH   = N / NCH;
    const int jc0   = blockIdx.y * JCH;

    // ---- persistent i-side fragments ----
    const size_t ti = ((size_t)itile * 64 + lane) * 8;
    short8 Bs  = *(const short8*)&sBi[ti];
    short8 Bfh = *(const short8*)&fBh[ti];
    short8 Bfl = *(const short8*)&fBl[ti];
    float nfin = -nf1[itile * 16 + m];

    v2f  sAB = {0.f, 0.f};             // (sum e^a, sum e^b)
    v2f  s2  = {0.f, 0.f};             // (sum e^2a, sum e^2b)
    float sab = 0.f;                   // sum e^a e^b

    const int tjbase = (b * N + jc0) >> 4;
    const short* gAs = sAj + (size_t)tjbase * 512;
    const short* gAh = fAh + (size_t)tjbase * 512;
    const short* gAl = fAl + (size_t)tjbase * 512;
    const float* gFn = fn2 + (size_t)b * N + jc0;

    for (int s0 = 0; s0 < JCH; s0 += STJ) {
        // ---- stage 4 tiles: three contiguous 4 KB copies + fn ----
        const int to = s0 * 4;                     // uint4 offset: 4 per j-row
        ((uint4*)lAs)[tid] = ((const uint4*)gAs)[to + tid];
        ((uint4*)lAh)[tid] = ((const uint4*)gAh)[to + tid];
        ((uint4*)lAl)[tid] = ((const uint4*)gAl)[to + tid];
        if (tid < STJ) lFn[tid] = gFn[s0 + tid];
        __syncthreads();

#pragma unroll 2
        for (int tt = 0; tt < STJ/16; ++tt) {
            const short8 As = *(const short8*)&lAs[(tt*64 + lane)*8];
            const short8 Ah = *(const short8*)&lAh[(tt*64 + lane)*8];
            const short8 Al = *(const short8*)&lAl[(tt*64 + lane)*8];
            floatx4 fnq = *(const floatx4*)&lFn[tt*16 + q*4];

            floatx4 cs = {0.f, 0.f, 0.f, 0.f};
            cs = __builtin_amdgcn_mfma_f32_16x16x32_bf16(As, Bs, cs, 0, 0, 0);

            floatx4 cf = {nfin - fnq[0], nfin - fnq[1],
                          nfin - fnq[2], nfin - fnq[3]};
            cf = __builtin_amdgcn_mfma_f32_16x16x32_bf16(Ah, Bfh, cf, 0, 0, 0);
            cf = __builtin_amdgcn_mfma_f32_16x16x32_bf16(Ah, Bfl, cf, 0, 0, 0);
            cf = __builtin_amdgcn_mfma_f32_16x16x32_bf16(Al, Bfh, cf, 0, 0, 0);

#pragma unroll
            for (int r = 0; r < 4; ++r) {
                float ea = fast_exp2(cs[r]);       // complete spatial logit
                float eb = fast_exp2(cf[r]);       // complete feature logit
                v2f e = {ea, eb};
                sAB += e;                               // v_pk_add_f32
                s2   = __builtin_elementwise_fma(e, e, s2);
                sab  = fmaf(ea, eb, sab);
            }
        }
        __syncthreads();
    }

    // ---- reduce the 4 j-quads (lanes sharing lane&15), then atomics ----
    float vA = sAB.x, vB = sAB.y, v2a = s2.x, v2b = s2.y, vab = sab;
    vA  += __shfl_xor(vA, 16);  vA  += __shfl_xor(vA, 32);
    vB  += __shfl_xor(vB, 16);  vB  += __shfl_xor(vB, 32);
    v2a += __shfl_xor(v2a, 16); v2a += __shfl_xor(v2a, 32);
    v2b += __shfl_xor(v2b, 16); v2b += __shfl_xor(v2b, 32);
    vab += __shfl_xor(vab, 16); vab += __shfl_xor(vab, 32);
    if (lane < 16) {
        int row = itile * 16 + lane;
        atomicAdd(&acc[0*BN + row], vA);
        atomicAdd(&acc[1*BN + row], v2a);
        atomicAdd(&acc[2*BN + row], vB);
        atomicAdd(&acc[3*BN + row], v2b);
        atomicAdd(&acc[4*BN + row], vab);
    }
}

// ---------------------------------------------------------------------------
// Kernel B: combine per-row sums, weight, reduce into out[b] (out zeroed by P).
//   out[b] = sum_i w_i * ( S2a/A^2 - 2*Sab/(A*B) + S2b/B^2 )
// ---------------------------------------------------------------------------
__global__ __launch_bounds__(BLK) void finalize_kernel(
    const float* __restrict__ acc,
    const float* __restrict__ weights,
    float* __restrict__ out,
    int N, int BN)
{
    int row = blockIdx.x * BLK + threadIdx.x;
    int b   = (blockIdx.x * BLK) / N;

    float A   = acc[0*BN + row];
    float S2a = acc[1*BN + row];
    float Bt  = acc[2*BN + row];
    float S2b = acc[3*BN + row];
    float Sab = acc[4*BN + row];
    float invA = 1.0f / A;
    float invB = 1.0f / Bt;
    float val  = S2a*invA*invA - 2.0f*Sab*invA*invB + S2b*invB*invB;
    float sum  = weights[row] * val;

    __shared__ float red[BLK/64];
    for (int off = 32; off > 0; off >>= 1)
        sum += __shfl_down(sum, off);
    if ((threadIdx.x & 63) == 0) red[threadIdx.x >> 6] = sum;
    __syncthreads();
    if (threadIdx.x == 0) {
        float s = 0.f;
#pragma unroll
        for (int w = 0; w < BLK/64; ++w) s += red[w];
        atomicAdd(&out[b], s);
    }
}

// ---------------------------------------------------------------------------
extern "C" void kernel_launch(void* const* d_in, const int* in_sizes, int n_in,
                              void* d_out, int out_size, void* d_ws, size_t ws_size,
                              hipStream_t stream) {
    const float* points  = (const float*)d_in[0];
    const float* fea1    = (const float*)d_in[1];
    const float* fea2    = (const float*)d_in[2];
    const float* weights = (const float*)d_in[3];
    float* out = (float*)d_out;

    int B  = out_size;          // 2
    int BN = in_sizes[3];       // B*N = 8192
    int N  = BN / B;            // 4096

    // workspace: acc | sAj | sBi | fAh | fAl | fBh | fBl | fn2 | nf1
    float* acc = (float*)d_ws;
    char*  p   = (char*)d_ws + (size_t)5 * BN * 4;
    short* sAj = (short*)p; p += (size_t)BN * 64;
    short* sBi = (short*)p; p += (size_t)BN * 64;
    short* fAh = (short*)p; p += (size_t)BN * 64;
    short* fAl = (short*)p; p += (size_t)BN * 64;
    short* fBh = (short*)p; p += (size_t)BN * 64;
    short* fBl = (short*)p; p += (size_t)BN * 64;
    float* fn2 = (float*)p; p += (size_t)BN * 4;
    float* nf1 = (float*)p;

    precompute_kernel<<<dim3((BN + BLK - 1) / BLK), dim3(BLK), 0, stream>>>(
        points, fea1, fea2, sAj, sBi, fAh, fAl, fBh, fBl, fn2, nf1,
        acc, out, BN, B);

    dim3 grid(BN / 64, NCH);    // 128 x 8 = 1024 blocks (full residency)
    pair_kernel<<<grid, dim3(BLK), 0, stream>>>(
        sAj, fAh, fAl, sBi, fBh, fBl, fn2, nf1, acc, N, BN);

    finalize_kernel<<<dim3(BN / BLK), dim3(BLK), 0, stream>>>(acc, weights, out, N, BN);
}